// Round 1
// baseline (3255.888 us; speedup 1.0000x reference)
//
#include <hip/hip_runtime.h>
#include <hip/hip_bf16.h>
#include <math.h>

// GGNN: N=50000 nodes, E=400000 edges, G=64 graphs, IN=64, OUT=128, 4 etypes, 8 steps.
// Round 1: correct fp32 baseline.
//   - CSR-by-dst built per launch (no scatter atomics in the hot loop)
//   - per step: GEMM_A (h -> [Wh x4 | gh], 896 cols), CSR aggregate, GEMM_B (a -> gi,
//     written over dead Wh region of O), fused GRU pointwise
//   - readout: LDS per-block graph accumulators + global atomics, then 64-logit kernel

#define NN 50000
#define NE 400000
#define NG 64
#define IND 64
#define OD 128
#define LDO 896   // O row: cols 0..511 = Wh[t] (later gi in 0..383), 512..895 = gh

// ---------------- init h = [node_features | 0] ----------------
__global__ void k_init_h(const float* __restrict__ nf, float* __restrict__ h) {
    int i = blockIdx.x * 256 + threadIdx.x;
    if (i >= NN * OD) return;
    int n = i >> 7, d = i & 127;
    h[i] = (d < IND) ? nf[n * IND + d] : 0.f;
}

// ---------------- CSR build ----------------
__global__ void k_count(const int* __restrict__ dst, int* __restrict__ deg) {
    int e = blockIdx.x * 256 + threadIdx.x;
    if (e < NE) atomicAdd(&deg[dst[e]], 1);
}

__global__ void k_scan(const int* __restrict__ deg, int* __restrict__ rowp,
                       int* __restrict__ cursor) {
    __shared__ int buf[1024];
    __shared__ int carry;
    int tid = threadIdx.x;
    if (tid == 0) { carry = 0; rowp[0] = 0; }
    __syncthreads();
    for (int base = 0; base < NN; base += 1024) {
        int i = base + tid;
        int v = (i < NN) ? deg[i] : 0;
        buf[tid] = v;
        __syncthreads();
        for (int off = 1; off < 1024; off <<= 1) {
            int t = (tid >= off) ? buf[tid - off] : 0;
            __syncthreads();
            if (tid >= off) buf[tid] += t;
            __syncthreads();
        }
        int incl = buf[tid] + carry;
        if (i < NN) { rowp[i + 1] = incl; cursor[i] = incl - v; }
        __syncthreads();
        if (tid == 1023) carry = incl;
        __syncthreads();
    }
}

__global__ void k_fill(const int* __restrict__ src, const int* __restrict__ dst,
                       const int* __restrict__ et, int* __restrict__ cursor,
                       int* __restrict__ ebase) {
    int e = blockIdx.x * 256 + threadIdx.x;
    if (e < NE) {
        int pos = atomicAdd(&cursor[dst[e]], 1);
        ebase[pos] = src[e] * LDO + et[e] * 128;   // row base into O for this edge's message
    }
}

// ---------------- tiled fp32 GEMM: C[m, g*128+o] = A[m,:] . W_g[o,:] + bias_g[o] -------
// A: M x 128 row-major. Group g: g<ngrp0 -> W0+g*16384, else W1+(g-ngrp0)*16384.
// 128x128 tile per block, 256 threads, 8x8 micro-tile, 32-k LDS chunks (stride 132).
__global__ __launch_bounds__(256) void k_gemm(
    const float* __restrict__ A, int M,
    const float* __restrict__ W0, const float* __restrict__ b0, int ngrp0,
    const float* __restrict__ W1, const float* __restrict__ b1,
    float* __restrict__ C) {
    __shared__ float At[32 * 132];
    __shared__ float Wt[32 * 132];

    const int g = blockIdx.y;
    const float* W;
    const float* bias;
    if (g < ngrp0) { W = W0 + (size_t)g * (128 * 128); bias = b0 + g * 128; }
    else           { W = W1 + (size_t)(g - ngrp0) * (128 * 128); bias = b1 + (g - ngrp0) * 128; }
    const int colbase = g * 128;
    const int m0 = blockIdx.x * 128;
    const int tid = threadIdx.x;

    const int kq = tid & 7;           // float4 index within 32-k chunk
    const int r0 = (tid >> 3) * 4;    // 4 staging rows per thread
    const int nl = (tid & 15) * 8;    // local node base (8 nodes)
    const int ol = (tid >> 4) * 8;    // local out base (8 outs)

    float bv[8];
#pragma unroll
    for (int j = 0; j < 8; ++j) bv[j] = bias[ol + j];

    float acc[8][8];
#pragma unroll
    for (int i = 0; i < 8; ++i)
#pragma unroll
        for (int j = 0; j < 8; ++j) acc[i][j] = 0.f;

    const float4* A4 = (const float4*)A;
    const float4* W4 = (const float4*)W;

    for (int c = 0; c < 4; ++c) {
        float4 av[4], wv[4];
#pragma unroll
        for (int i = 0; i < 4; ++i) {
            int n = m0 + r0 + i;
            av[i] = (n < M) ? A4[(size_t)n * 32 + c * 8 + kq] : make_float4(0.f, 0.f, 0.f, 0.f);
            wv[i] = W4[(size_t)(r0 + i) * 32 + c * 8 + kq];
        }
        __syncthreads();   // previous chunk fully consumed
#pragma unroll
        for (int j = 0; j < 4; ++j) {
            float4 ta, tw;
            ta.x = ((const float*)&av[0])[j]; ta.y = ((const float*)&av[1])[j];
            ta.z = ((const float*)&av[2])[j]; ta.w = ((const float*)&av[3])[j];
            tw.x = ((const float*)&wv[0])[j]; tw.y = ((const float*)&wv[1])[j];
            tw.z = ((const float*)&wv[2])[j]; tw.w = ((const float*)&wv[3])[j];
            *(float4*)&At[(kq * 4 + j) * 132 + r0] = ta;   // At[k][n] = A[n][k]
            *(float4*)&Wt[(kq * 4 + j) * 132 + r0] = tw;   // Wt[k][o] = W[o][k]
        }
        __syncthreads();
#pragma unroll
        for (int k = 0; k < 32; ++k) {
            float4 a0 = *(const float4*)&At[k * 132 + nl];
            float4 a1 = *(const float4*)&At[k * 132 + nl + 4];
            float4 w0 = *(const float4*)&Wt[k * 132 + ol];
            float4 w1 = *(const float4*)&Wt[k * 132 + ol + 4];
            float aa[8] = {a0.x, a0.y, a0.z, a0.w, a1.x, a1.y, a1.z, a1.w};
            float ww[8] = {w0.x, w0.y, w0.z, w0.w, w1.x, w1.y, w1.z, w1.w};
#pragma unroll
            for (int i = 0; i < 8; ++i)
#pragma unroll
                for (int j = 0; j < 8; ++j) acc[i][j] += aa[i] * ww[j];
        }
    }

#pragma unroll
    for (int i = 0; i < 8; ++i) {
        int n = m0 + nl + i;
        if (n < M) {
            float* crow = C + (size_t)n * LDO + colbase + ol;
            float4 o0, o1;
            o0.x = acc[i][0] + bv[0]; o0.y = acc[i][1] + bv[1];
            o0.z = acc[i][2] + bv[2]; o0.w = acc[i][3] + bv[3];
            o1.x = acc[i][4] + bv[4]; o1.y = acc[i][5] + bv[5];
            o1.z = acc[i][6] + bv[6]; o1.w = acc[i][7] + bv[7];
            *(float4*)&crow[0] = o0;
            *(float4*)&crow[4] = o1;
        }
    }
}

// ---------------- CSR aggregate: a[n][d] = sum over in-edges of O[ebase + d] ----------
__global__ void k_aggregate(const float* __restrict__ O, const int* __restrict__ rowp,
                            const int* __restrict__ ebase, float* __restrict__ a) {
    int n = blockIdx.x * 2 + (threadIdx.x >> 7);
    int d = threadIdx.x & 127;
    if (n >= NN) return;
    int beg = rowp[n], end = rowp[n + 1];
    float acc = 0.f;
    for (int i = beg; i < end; ++i) {
        int b = ebase[i];
        acc += O[b + d];
    }
    a[n * OD + d] = acc;
}

// ---------------- fused GRU pointwise ----------------
__global__ void k_gru(const float* __restrict__ O, float* __restrict__ h) {
    int i = blockIdx.x * 256 + threadIdx.x;
    if (i >= NN * OD) return;
    int n = i >> 7, d = i & 127;
    const float* r = O + (size_t)n * LDO;
    float ir = r[d], iz = r[128 + d], in_ = r[256 + d];
    float hr = r[512 + d], hz = r[640 + d], hn = r[768 + d];
    float rg = 1.f / (1.f + __expf(-(ir + hr)));
    float zg = 1.f / (1.f + __expf(-(iz + hz)));
    float ng = tanhf(in_ + rg * hn);
    h[i] = (1.f - zg) * ng + zg * h[i];
}

// ---------------- graph readout: feats[g][0..191] = sum hcat over nodes of g ----------
__global__ void k_readout(const float* __restrict__ h, const float* __restrict__ nf,
                          const int* __restrict__ gid, float* __restrict__ feats) {
    __shared__ float sh[NG * 192];
    int d = threadIdx.x;   // 0..191, owns dim d exclusively -> no LDS races
    for (int i = d; i < NG * 192; i += 192) sh[i] = 0.f;
    __syncthreads();
    int chunk = (NN + gridDim.x - 1) / gridDim.x;
    int n0 = blockIdx.x * chunk;
    int n1 = n0 + chunk; if (n1 > NN) n1 = NN;
    for (int n = n0; n < n1; ++n) {
        int g = gid[n];
        float v = (d < OD) ? h[(size_t)n * OD + d] : nf[(size_t)n * IND + (d - OD)];
        sh[g * 192 + d] += v;
    }
    __syncthreads();
    for (int g = 0; g < NG; ++g) atomicAdd(&feats[g * 192 + d], sh[g * 192 + d]);
}

__global__ void k_final(const float* __restrict__ feats, const float* __restrict__ W_cls,
                        const float* __restrict__ b_cls, float* __restrict__ out) {
    int g = threadIdx.x;
    if (g >= NG) return;
    float acc = b_cls[0];
    for (int d = 0; d < 192; ++d) acc += feats[g * 192 + d] * W_cls[d];
    out[g] = 1.f / (1.f + __expf(-acc));
}

extern "C" void kernel_launch(void* const* d_in, const int* in_sizes, int n_in,
                              void* d_out, int out_size, void* d_ws, size_t ws_size,
                              hipStream_t stream) {
    const float* nf    = (const float*)d_in[0];
    const int*   src   = (const int*)d_in[1];
    const int*   dst   = (const int*)d_in[2];
    const int*   et    = (const int*)d_in[3];
    const int*   gid   = (const int*)d_in[4];
    const float* Ws    = (const float*)d_in[5];
    const float* bs    = (const float*)d_in[6];
    const float* W_ih  = (const float*)d_in[7];
    const float* W_hh  = (const float*)d_in[8];
    const float* b_ih  = (const float*)d_in[9];
    const float* b_hh  = (const float*)d_in[10];
    const float* W_cls = (const float*)d_in[11];
    const float* b_cls = (const float*)d_in[12];
    float* out = (float*)d_out;

    char* ws = (char*)d_ws;
    size_t off = 0;
    auto alloc = [&](size_t bytes) -> void* {
        off = (off + 255) & ~(size_t)255;
        void* p = ws + off;
        off += bytes;
        return p;
    };
    float* h     = (float*)alloc((size_t)NN * OD * 4);        // 25.6 MB
    float* O     = (float*)alloc((size_t)NN * LDO * 4);       // 179.2 MB
    float* a     = (float*)alloc((size_t)NN * OD * 4);        // 25.6 MB
    int*   deg   = (int*)alloc((size_t)NN * 4);
    int*   rowp  = (int*)alloc((size_t)(NN + 1) * 4);
    int*   cursor= (int*)alloc((size_t)NN * 4);
    int*   ebase = (int*)alloc((size_t)NE * 4);
    float* feats = (float*)alloc((size_t)NG * 192 * 4);
    (void)ws_size; (void)in_sizes; (void)n_in; (void)out_size;

    hipMemsetAsync(deg, 0, (size_t)NN * 4, stream);
    hipMemsetAsync(feats, 0, (size_t)NG * 192 * 4, stream);

    k_init_h<<<(NN * OD + 255) / 256, 256, 0, stream>>>(nf, h);
    k_count<<<(NE + 255) / 256, 256, 0, stream>>>(dst, deg);
    k_scan<<<1, 1024, 0, stream>>>(deg, rowp, cursor);
    k_fill<<<(NE + 255) / 256, 256, 0, stream>>>(src, dst, et, cursor, ebase);

    const int mt = (NN + 127) / 128;   // 391 node tiles
    for (int s = 0; s < 8; ++s) {
        // O[:, 0..511] = Wh per etype; O[:, 512..895] = gh
        k_gemm<<<dim3(mt, 7), 256, 0, stream>>>(h, NN, Ws, bs, 4, W_hh, b_hh, O);
        k_aggregate<<<(NN + 1) / 2, 256, 0, stream>>>(O, rowp, ebase, a);
        // gi over dead Wh region: O[:, 0..383]
        k_gemm<<<dim3(mt, 3), 256, 0, stream>>>(a, NN, W_ih, b_ih, 3, W_ih, b_ih, O);
        k_gru<<<(NN * OD + 255) / 256, 256, 0, stream>>>(O, h);
    }

    k_readout<<<64, 192, 0, stream>>>(h, nf, gid, feats);
    k_final<<<1, 64, 0, stream>>>(feats, W_cls, b_cls, out);
}

// Round 2
// 2963.586 us; speedup vs baseline: 1.0986x; 1.0986x over previous
//
#include <hip/hip_runtime.h>
#include <hip/hip_bf16.h>
#include <math.h>

// GGNN: N=50000 nodes, E=400000 edges, G=64 graphs, IN=64, OUT=128, 4 etypes, 8 steps.
// R2: parallel CSR scan (3-phase) + parallel readout (256 blocks + reduce).
//   - CSR-by-dst built per launch (no scatter atomics in the hot loop)
//   - per step: GEMM_A (h -> [Wh x4 | gh], 896 cols), CSR aggregate, GEMM_B (a -> gi,
//     written over dead Wh region of O), fused GRU pointwise
//   - readout: per-block LDS graph accumulators -> global partials (aliased on dead O)
//     -> reduce kernel -> 64-logit kernel

#define NN 50000
#define NE 400000
#define NG 64
#define IND 64
#define OD 128
#define LDO 896   // O row: cols 0..511 = Wh[t] (later gi in 0..383), 512..895 = gh
#define RB 256    // readout blocks

// ---------------- init h = [node_features | 0] ----------------
__global__ void k_init_h(const float* __restrict__ nf, float* __restrict__ h) {
    int i = blockIdx.x * 256 + threadIdx.x;
    if (i >= NN * OD) return;
    int n = i >> 7, d = i & 127;
    h[i] = (d < IND) ? nf[n * IND + d] : 0.f;
}

// ---------------- CSR build ----------------
__global__ void k_count(const int* __restrict__ dst, int* __restrict__ deg) {
    int e = blockIdx.x * 256 + threadIdx.x;
    if (e < NE) atomicAdd(&deg[dst[e]], 1);
}

// phase 1: per-block (1024-wide) inclusive scan; block sums out
__global__ void k_scan1(const int* __restrict__ deg, int* __restrict__ rowp,
                        int* __restrict__ bsum) {
    __shared__ int buf[1024];
    int tid = threadIdx.x;
    int i = blockIdx.x * 1024 + tid;
    int v = (i < NN) ? deg[i] : 0;
    buf[tid] = v;
    __syncthreads();
    for (int off = 1; off < 1024; off <<= 1) {
        int t = (tid >= off) ? buf[tid - off] : 0;
        __syncthreads();
        buf[tid] += t;
        __syncthreads();
    }
    if (i < NN) rowp[i + 1] = buf[tid];
    if (tid == 1023) bsum[blockIdx.x] = buf[tid];
}

// phase 2: scan the (<=64) block sums -> exclusive offsets
__global__ void k_scan2(int* __restrict__ bsum, int nb) {
    __shared__ int buf[64];
    int tid = threadIdx.x;
    int v = (tid < nb) ? bsum[tid] : 0;
    buf[tid] = v;
    __syncthreads();
    for (int off = 1; off < 64; off <<= 1) {
        int t = (tid >= off) ? buf[tid - off] : 0;
        __syncthreads();
        buf[tid] += t;
        __syncthreads();
    }
    if (tid < nb) bsum[tid] = buf[tid] - v;   // exclusive
}

// phase 3: add block offsets; derive cursor
__global__ void k_scan3(const int* __restrict__ deg, const int* __restrict__ bsum,
                        int* __restrict__ rowp, int* __restrict__ cursor) {
    int i = blockIdx.x * 256 + threadIdx.x;
    if (i >= NN) return;
    int incl = rowp[i + 1] + bsum[i >> 10];
    rowp[i + 1] = incl;
    cursor[i] = incl - deg[i];
    if (i == 0) rowp[0] = 0;
}

__global__ void k_fill(const int* __restrict__ src, const int* __restrict__ dst,
                       const int* __restrict__ et, int* __restrict__ cursor,
                       int* __restrict__ ebase) {
    int e = blockIdx.x * 256 + threadIdx.x;
    if (e < NE) {
        int pos = atomicAdd(&cursor[dst[e]], 1);
        ebase[pos] = src[e] * LDO + et[e] * 128;   // row base into O for this edge's message
    }
}

// ---------------- tiled fp32 GEMM: C[m, g*128+o] = A[m,:] . W_g[o,:] + bias_g[o] -------
// A: M x 128 row-major. Group g: g<ngrp0 -> W0+g*16384, else W1+(g-ngrp0)*16384.
// 128x128 tile per block, 256 threads, 8x8 micro-tile, 32-k LDS chunks (stride 132).
__global__ __launch_bounds__(256) void k_gemm(
    const float* __restrict__ A, int M,
    const float* __restrict__ W0, const float* __restrict__ b0, int ngrp0,
    const float* __restrict__ W1, const float* __restrict__ b1,
    float* __restrict__ C) {
    __shared__ float At[32 * 132];
    __shared__ float Wt[32 * 132];

    const int g = blockIdx.y;
    const float* W;
    const float* bias;
    if (g < ngrp0) { W = W0 + (size_t)g * (128 * 128); bias = b0 + g * 128; }
    else           { W = W1 + (size_t)(g - ngrp0) * (128 * 128); bias = b1 + (g - ngrp0) * 128; }
    const int colbase = g * 128;
    const int m0 = blockIdx.x * 128;
    const int tid = threadIdx.x;

    const int kq = tid & 7;           // float4 index within 32-k chunk
    const int r0 = (tid >> 3) * 4;    // 4 staging rows per thread
    const int nl = (tid & 15) * 8;    // local node base (8 nodes)
    const int ol = (tid >> 4) * 8;    // local out base (8 outs)

    float bv[8];
#pragma unroll
    for (int j = 0; j < 8; ++j) bv[j] = bias[ol + j];

    float acc[8][8];
#pragma unroll
    for (int i = 0; i < 8; ++i)
#pragma unroll
        for (int j = 0; j < 8; ++j) acc[i][j] = 0.f;

    const float4* A4 = (const float4*)A;
    const float4* W4 = (const float4*)W;

    for (int c = 0; c < 4; ++c) {
        float4 av[4], wv[4];
#pragma unroll
        for (int i = 0; i < 4; ++i) {
            int n = m0 + r0 + i;
            av[i] = (n < M) ? A4[(size_t)n * 32 + c * 8 + kq] : make_float4(0.f, 0.f, 0.f, 0.f);
            wv[i] = W4[(size_t)(r0 + i) * 32 + c * 8 + kq];
        }
        __syncthreads();   // previous chunk fully consumed
#pragma unroll
        for (int j = 0; j < 4; ++j) {
            float4 ta, tw;
            ta.x = ((const float*)&av[0])[j]; ta.y = ((const float*)&av[1])[j];
            ta.z = ((const float*)&av[2])[j]; ta.w = ((const float*)&av[3])[j];
            tw.x = ((const float*)&wv[0])[j]; tw.y = ((const float*)&wv[1])[j];
            tw.z = ((const float*)&wv[2])[j]; tw.w = ((const float*)&wv[3])[j];
            *(float4*)&At[(kq * 4 + j) * 132 + r0] = ta;   // At[k][n] = A[n][k]
            *(float4*)&Wt[(kq * 4 + j) * 132 + r0] = tw;   // Wt[k][o] = W[o][k]
        }
        __syncthreads();
#pragma unroll
        for (int k = 0; k < 32; ++k) {
            float4 a0 = *(const float4*)&At[k * 132 + nl];
            float4 a1 = *(const float4*)&At[k * 132 + nl + 4];
            float4 w0 = *(const float4*)&Wt[k * 132 + ol];
            float4 w1 = *(const float4*)&Wt[k * 132 + ol + 4];
            float aa[8] = {a0.x, a0.y, a0.z, a0.w, a1.x, a1.y, a1.z, a1.w};
            float ww[8] = {w0.x, w0.y, w0.z, w0.w, w1.x, w1.y, w1.z, w1.w};
#pragma unroll
            for (int i = 0; i < 8; ++i)
#pragma unroll
                for (int j = 0; j < 8; ++j) acc[i][j] += aa[i] * ww[j];
        }
    }

#pragma unroll
    for (int i = 0; i < 8; ++i) {
        int n = m0 + nl + i;
        if (n < M) {
            float* crow = C + (size_t)n * LDO + colbase + ol;
            float4 o0, o1;
            o0.x = acc[i][0] + bv[0]; o0.y = acc[i][1] + bv[1];
            o0.z = acc[i][2] + bv[2]; o0.w = acc[i][3] + bv[3];
            o1.x = acc[i][4] + bv[4]; o1.y = acc[i][5] + bv[5];
            o1.z = acc[i][6] + bv[6]; o1.w = acc[i][7] + bv[7];
            *(float4*)&crow[0] = o0;
            *(float4*)&crow[4] = o1;
        }
    }
}

// ---------------- CSR aggregate: a[n][d] = sum over in-edges of O[ebase + d] ----------
__global__ void k_aggregate(const float* __restrict__ O, const int* __restrict__ rowp,
                            const int* __restrict__ ebase, float* __restrict__ a) {
    int n = blockIdx.x * 2 + (threadIdx.x >> 7);
    int d = threadIdx.x & 127;
    if (n >= NN) return;
    int beg = rowp[n], end = rowp[n + 1];
    float acc = 0.f;
    for (int i = beg; i < end; ++i) {
        int b = ebase[i];
        acc += O[b + d];
    }
    a[n * OD + d] = acc;
}

// ---------------- fused GRU pointwise ----------------
__global__ void k_gru(const float* __restrict__ O, float* __restrict__ h) {
    int i = blockIdx.x * 256 + threadIdx.x;
    if (i >= NN * OD) return;
    int n = i >> 7, d = i & 127;
    const float* r = O + (size_t)n * LDO;
    float ir = r[d], iz = r[128 + d], in_ = r[256 + d];
    float hr = r[512 + d], hz = r[640 + d], hn = r[768 + d];
    float rg = 1.f / (1.f + __expf(-(ir + hr)));
    float zg = 1.f / (1.f + __expf(-(iz + hz)));
    float ng = tanhf(in_ + rg * hn);
    h[i] = (1.f - zg) * ng + zg * h[i];
}

// ---------------- graph readout, stage 1: per-block partial sums ----------------
// partial[blk][g*192+d] = sum over block's node chunk
__global__ void k_readout(const float* __restrict__ h, const float* __restrict__ nf,
                          const int* __restrict__ gid, float* __restrict__ partial) {
    __shared__ float sh[NG * 192];
    int d = threadIdx.x;   // 0..191, owns dim d exclusively -> no LDS races
    for (int i = d; i < NG * 192; i += 192) sh[i] = 0.f;
    __syncthreads();
    int chunk = (NN + RB - 1) / RB;
    int n0 = blockIdx.x * chunk;
    int n1 = n0 + chunk; if (n1 > NN) n1 = NN;
    for (int n = n0; n < n1; ++n) {
        int g = gid[n];
        float v = (d < OD) ? h[(size_t)n * OD + d] : nf[(size_t)n * IND + (d - OD)];
        sh[g * 192 + d] += v;
    }
    __syncthreads();
    float* p = partial + (size_t)blockIdx.x * (NG * 192);
    for (int i = d; i < NG * 192; i += 192) p[i] = sh[i];
}

// ---------------- readout, stage 2: reduce partials ----------------
__global__ void k_reduce(const float* __restrict__ partial, float* __restrict__ feats) {
    int i = blockIdx.x * 256 + threadIdx.x;
    if (i >= NG * 192) return;
    float s = 0.f;
    for (int b = 0; b < RB; ++b) s += partial[(size_t)b * (NG * 192) + i];
    feats[i] = s;
}

__global__ void k_final(const float* __restrict__ feats, const float* __restrict__ W_cls,
                        const float* __restrict__ b_cls, float* __restrict__ out) {
    int g = threadIdx.x;
    if (g >= NG) return;
    float acc = b_cls[0];
    for (int d = 0; d < 192; ++d) acc += feats[g * 192 + d] * W_cls[d];
    out[g] = 1.f / (1.f + __expf(-acc));
}

extern "C" void kernel_launch(void* const* d_in, const int* in_sizes, int n_in,
                              void* d_out, int out_size, void* d_ws, size_t ws_size,
                              hipStream_t stream) {
    const float* nf    = (const float*)d_in[0];
    const int*   src   = (const int*)d_in[1];
    const int*   dst   = (const int*)d_in[2];
    const int*   et    = (const int*)d_in[3];
    const int*   gid   = (const int*)d_in[4];
    const float* Ws    = (const float*)d_in[5];
    const float* bs    = (const float*)d_in[6];
    const float* W_ih  = (const float*)d_in[7];
    const float* W_hh  = (const float*)d_in[8];
    const float* b_ih  = (const float*)d_in[9];
    const float* b_hh  = (const float*)d_in[10];
    const float* W_cls = (const float*)d_in[11];
    const float* b_cls = (const float*)d_in[12];
    float* out = (float*)d_out;

    char* ws = (char*)d_ws;
    size_t off = 0;
    auto alloc = [&](size_t bytes) -> void* {
        off = (off + 255) & ~(size_t)255;
        void* p = ws + off;
        off += bytes;
        return p;
    };
    float* h     = (float*)alloc((size_t)NN * OD * 4);        // 25.6 MB
    float* O     = (float*)alloc((size_t)NN * LDO * 4);       // 179.2 MB
    float* a     = (float*)alloc((size_t)NN * OD * 4);        // 25.6 MB
    int*   deg   = (int*)alloc((size_t)NN * 4);
    int*   rowp  = (int*)alloc((size_t)(NN + 1) * 4);
    int*   cursor= (int*)alloc((size_t)NN * 4);
    int*   ebase = (int*)alloc((size_t)NE * 4);
    int*   bsum  = (int*)alloc(64 * 4);
    float* feats = (float*)alloc((size_t)NG * 192 * 4);
    (void)ws_size; (void)in_sizes; (void)n_in; (void)out_size;

    // readout partials alias the (dead-by-then) O buffer: RB*12288*4 = 12.6 MB << 179 MB
    float* partial = O;

    hipMemsetAsync(deg, 0, (size_t)NN * 4, stream);

    k_init_h<<<(NN * OD + 255) / 256, 256, 0, stream>>>(nf, h);
    k_count<<<(NE + 255) / 256, 256, 0, stream>>>(dst, deg);
    const int nb = (NN + 1023) / 1024;   // 49
    k_scan1<<<nb, 1024, 0, stream>>>(deg, rowp, bsum);
    k_scan2<<<1, 64, 0, stream>>>(bsum, nb);
    k_scan3<<<(NN + 255) / 256, 256, 0, stream>>>(deg, bsum, rowp, cursor);
    k_fill<<<(NE + 255) / 256, 256, 0, stream>>>(src, dst, et, cursor, ebase);

    const int mt = (NN + 127) / 128;   // 391 node tiles
    for (int s = 0; s < 8; ++s) {
        // O[:, 0..511] = Wh per etype; O[:, 512..895] = gh
        k_gemm<<<dim3(mt, 7), 256, 0, stream>>>(h, NN, Ws, bs, 4, W_hh, b_hh, O);
        k_aggregate<<<(NN + 1) / 2, 256, 0, stream>>>(O, rowp, ebase, a);
        // gi over dead Wh region: O[:, 0..383]
        k_gemm<<<dim3(mt, 3), 256, 0, stream>>>(a, NN, W_ih, b_ih, 3, W_ih, b_ih, O);
        k_gru<<<(NN * OD + 255) / 256, 256, 0, stream>>>(O, h);
    }

    k_readout<<<RB, 192, 0, stream>>>(h, nf, gid, partial);
    k_reduce<<<(NG * 192 + 255) / 256, 256, 0, stream>>>(partial, feats);
    k_final<<<1, 64, 0, stream>>>(feats, W_cls, b_cls, out);
}

// Round 4
// 1632.651 us; speedup vs baseline: 1.9942x; 1.8152x over previous
//
#include <hip/hip_runtime.h>
#include <hip/hip_bf16.h>
#include <math.h>

// GGNN: N=50000 nodes, E=400000 edges, G=64 graphs, IN=64, OUT=128, 4 etypes, 8 steps.
// R4: fp16 MFMA GEMMs (mfma_f32_16x16x32_f16, fp32 accumulate).
//   bf16 failed accuracy (absmax 6.6e-2 > 2e-2): eps 3.9e-3 re-quantization each of 8
//   steps compounds through the 780-node/graph readout sum. fp16 eps = 4.9e-4 (8x finer),
//   values bounded (|h|<~5, |a|<~50, |W|<0.09) -> safe range, predicted absmax ~8e-3.
//   - master h stays fp32 (GRU recurrence); fp16 shadows hb/ab feed the GEMMs
//   - K=128 = one LDS tile, no K-loop; 128x128 block tile, 4 waves, 64 MFMA/wave
//   - LDS stride 136 halfs -> bank-balanced b128 reads/writes
//   - CSR-by-dst, per step: GEMM_A (hb -> [Wh x4 | gh]), aggregate (-> ab fp16),
//     GEMM_B (ab -> gi over dead Wh region), fused GRU pointwise

#define NN 50000
#define NE 400000
#define NG 64
#define IND 64
#define OD 128
#define LDO 896   // O row: cols 0..511 = Wh[t] (later gi in 0..383), 512..895 = gh
#define RB 256    // readout blocks

typedef _Float16 f16x8 __attribute__((ext_vector_type(8)));
typedef float f32x4 __attribute__((ext_vector_type(4)));

__device__ inline unsigned short f2h(float x) {
    _Float16 hv = (_Float16)x;
    unsigned short u;
    __builtin_memcpy(&u, &hv, 2);
    return u;
}

// ---------------- fp32 -> fp16 weight conversion ----------------
__global__ void k_cvt(const float* __restrict__ s, unsigned short* __restrict__ d, int n) {
    int i = blockIdx.x * 256 + threadIdx.x;
    if (i < n) d[i] = f2h(s[i]);
}

// ---------------- init h = [node_features | 0] (fp32 + fp16 shadow) ----------------
__global__ void k_init_h(const float* __restrict__ nf, float* __restrict__ h,
                         unsigned short* __restrict__ hb) {
    int i = blockIdx.x * 256 + threadIdx.x;
    if (i >= NN * OD) return;
    int n = i >> 7, d = i & 127;
    float v = (d < IND) ? nf[n * IND + d] : 0.f;
    h[i] = v;
    hb[i] = f2h(v);
}

// ---------------- CSR build ----------------
__global__ void k_count(const int* __restrict__ dst, int* __restrict__ deg) {
    int e = blockIdx.x * 256 + threadIdx.x;
    if (e < NE) atomicAdd(&deg[dst[e]], 1);
}

__global__ void k_scan1(const int* __restrict__ deg, int* __restrict__ rowp,
                        int* __restrict__ bsum) {
    __shared__ int buf[1024];
    int tid = threadIdx.x;
    int i = blockIdx.x * 1024 + tid;
    int v = (i < NN) ? deg[i] : 0;
    buf[tid] = v;
    __syncthreads();
    for (int off = 1; off < 1024; off <<= 1) {
        int t = (tid >= off) ? buf[tid - off] : 0;
        __syncthreads();
        buf[tid] += t;
        __syncthreads();
    }
    if (i < NN) rowp[i + 1] = buf[tid];
    if (tid == 1023) bsum[blockIdx.x] = buf[tid];
}

__global__ void k_scan2(int* __restrict__ bsum, int nb) {
    __shared__ int buf[64];
    int tid = threadIdx.x;
    int v = (tid < nb) ? bsum[tid] : 0;
    buf[tid] = v;
    __syncthreads();
    for (int off = 1; off < 64; off <<= 1) {
        int t = (tid >= off) ? buf[tid - off] : 0;
        __syncthreads();
        buf[tid] += t;
        __syncthreads();
    }
    if (tid < nb) bsum[tid] = buf[tid] - v;   // exclusive
}

__global__ void k_scan3(const int* __restrict__ deg, const int* __restrict__ bsum,
                        int* __restrict__ rowp, int* __restrict__ cursor) {
    int i = blockIdx.x * 256 + threadIdx.x;
    if (i >= NN) return;
    int incl = rowp[i + 1] + bsum[i >> 10];
    rowp[i + 1] = incl;
    cursor[i] = incl - deg[i];
    if (i == 0) rowp[0] = 0;
}

__global__ void k_fill(const int* __restrict__ src, const int* __restrict__ dst,
                       const int* __restrict__ et, int* __restrict__ cursor,
                       int* __restrict__ ebase) {
    int e = blockIdx.x * 256 + threadIdx.x;
    if (e < NE) {
        int pos = atomicAdd(&cursor[dst[e]], 1);
        ebase[pos] = src[e] * LDO + et[e] * 128;   // row base into O for this edge's message
    }
}

// ---------------- fp16 MFMA GEMM: C[m, g*128+o] = A[m,:] . W_g[o,:] + bias_g[o] -------
// A: M x 128 fp16 row-major. W group g: 128(out) x 128(in) fp16 row-major.
// Block: 256 thr (4 waves), tile 128 nodes x 128 outs, K=128 in one LDS tile.
// Wave w: rows [w*32, w*32+32) x all 128 cols; 2x8 mfma tiles x 4 k-steps.
// Verified layouts (guide §3, dtype-independent): A[m=lane&15][k=quad*8+j],
// B[k=quad*8+j][n=lane&15], C/D[row=quad*4+reg][col=lane&15].
__global__ __launch_bounds__(256) void k_gemm_mfma(
    const unsigned short* __restrict__ Ab, int M,
    const unsigned short* __restrict__ W0, const float* __restrict__ b0, int ngrp0,
    const unsigned short* __restrict__ W1, const float* __restrict__ b1,
    float* __restrict__ C) {
    __shared__ unsigned short As[128 * 136];   // stride 136 halfs = 272 B (bank-balanced)
    __shared__ unsigned short Bs[128 * 136];

    const int g = blockIdx.y;
    const unsigned short* W;
    const float* bias;
    if (g < ngrp0) { W = W0 + (size_t)g * 16384; bias = b0 + g * 128; }
    else           { W = W1 + (size_t)(g - ngrp0) * 16384; bias = b1 + (g - ngrp0) * 128; }
    const int colbase = g * 128;
    const int m0 = blockIdx.x * 128;
    const int tid = threadIdx.x;

    const uint4* A4 = (const uint4*)Ab;   // 16 uint4 per 128-col fp16 row
    const uint4* W4 = (const uint4*)W;

#pragma unroll
    for (int i = tid; i < 2048; i += 256) {
        int row = i >> 4, qq = i & 15;
        int n = m0 + row;
        uint4 va = (n < M) ? A4[(size_t)n * 16 + qq] : make_uint4(0u, 0u, 0u, 0u);
        *(uint4*)&As[row * 136 + qq * 8] = va;
        *(uint4*)&Bs[row * 136 + qq * 8] = W4[(size_t)row * 16 + qq];
    }
    __syncthreads();

    const int lane = tid & 63;
    const int w = tid >> 6;
    const int lr = lane & 15;     // row/col within 16-tile
    const int q = lane >> 4;      // quad

    float bv[8];
#pragma unroll
    for (int nt = 0; nt < 8; ++nt) bv[nt] = bias[nt * 16 + lr];

    f32x4 acc[2][8];
#pragma unroll
    for (int mt = 0; mt < 2; ++mt)
#pragma unroll
        for (int nt = 0; nt < 8; ++nt) acc[mt][nt] = (f32x4){0.f, 0.f, 0.f, 0.f};

#pragma unroll
    for (int ks = 0; ks < 4; ++ks) {
        f16x8 af[2];
#pragma unroll
        for (int mt = 0; mt < 2; ++mt)
            af[mt] = *(const f16x8*)&As[(w * 32 + mt * 16 + lr) * 136 + ks * 32 + q * 8];
        f16x8 bfr[8];
#pragma unroll
        for (int nt = 0; nt < 8; ++nt)
            bfr[nt] = *(const f16x8*)&Bs[(nt * 16 + lr) * 136 + ks * 32 + q * 8];
#pragma unroll
        for (int mt = 0; mt < 2; ++mt)
#pragma unroll
            for (int nt = 0; nt < 8; ++nt)
                acc[mt][nt] = __builtin_amdgcn_mfma_f32_16x16x32_f16(
                    af[mt], bfr[nt], acc[mt][nt], 0, 0, 0);
    }

#pragma unroll
    for (int mt = 0; mt < 2; ++mt) {
        int rowbase = m0 + w * 32 + mt * 16 + q * 4;
#pragma unroll
        for (int r = 0; r < 4; ++r) {
            int n = rowbase + r;
            if (n < M) {
                float* crow = C + (size_t)n * LDO + colbase;
#pragma unroll
                for (int nt = 0; nt < 8; ++nt)
                    crow[nt * 16 + lr] = acc[mt][nt][r] + bv[nt];
            }
        }
    }
}

// ---------------- CSR aggregate: ab[n][d] = fp16( sum over in-edges of O[ebase+d] ) ---
__global__ void k_aggregate(const float* __restrict__ O, const int* __restrict__ rowp,
                            const int* __restrict__ ebase, unsigned short* __restrict__ ab) {
    int n = blockIdx.x * 2 + (threadIdx.x >> 7);
    int d = threadIdx.x & 127;
    if (n >= NN) return;
    int beg = rowp[n], end = rowp[n + 1];
    float acc = 0.f;
    for (int i = beg; i < end; ++i) {
        int b = ebase[i];
        acc += O[b + d];
    }
    ab[n * OD + d] = f2h(acc);
}

// ---------------- fused GRU pointwise ----------------
__global__ void k_gru(const float* __restrict__ O, float* __restrict__ h,
                      unsigned short* __restrict__ hb) {
    int i = blockIdx.x * 256 + threadIdx.x;
    if (i >= NN * OD) return;
    int n = i >> 7, d = i & 127;
    const float* r = O + (size_t)n * LDO;
    float ir = r[d], iz = r[128 + d], in_ = r[256 + d];
    float hr = r[512 + d], hz = r[640 + d], hn = r[768 + d];
    float rg = 1.f / (1.f + __expf(-(ir + hr)));
    float zg = 1.f / (1.f + __expf(-(iz + hz)));
    float ng = tanhf(in_ + rg * hn);
    float nh = (1.f - zg) * ng + zg * h[i];
    h[i] = nh;
    hb[i] = f2h(nh);
}

// ---------------- graph readout, stage 1: per-block partial sums ----------------
__global__ void k_readout(const float* __restrict__ h, const float* __restrict__ nf,
                          const int* __restrict__ gid, float* __restrict__ partial) {
    __shared__ float sh[NG * 192];
    int d = threadIdx.x;   // 0..191, owns dim d exclusively -> no LDS races
    for (int i = d; i < NG * 192; i += 192) sh[i] = 0.f;
    __syncthreads();
    int chunk = (NN + RB - 1) / RB;
    int n0 = blockIdx.x * chunk;
    int n1 = n0 + chunk; if (n1 > NN) n1 = NN;
    for (int n = n0; n < n1; ++n) {
        int g = gid[n];
        float v = (d < OD) ? h[(size_t)n * OD + d] : nf[(size_t)n * IND + (d - OD)];
        sh[g * 192 + d] += v;
    }
    __syncthreads();
    float* p = partial + (size_t)blockIdx.x * (NG * 192);
    for (int i = d; i < NG * 192; i += 192) p[i] = sh[i];
}

// ---------------- readout, stage 2: reduce partials ----------------
__global__ void k_reduce(const float* __restrict__ partial, float* __restrict__ feats) {
    int i = blockIdx.x * 256 + threadIdx.x;
    if (i >= NG * 192) return;
    float s = 0.f;
    for (int b = 0; b < RB; ++b) s += partial[(size_t)b * (NG * 192) + i];
    feats[i] = s;
}

__global__ void k_final(const float* __restrict__ feats, const float* __restrict__ W_cls,
                        const float* __restrict__ b_cls, float* __restrict__ out) {
    int g = threadIdx.x;
    if (g >= NG) return;
    float acc = b_cls[0];
    for (int d = 0; d < 192; ++d) acc += feats[g * 192 + d] * W_cls[d];
    out[g] = 1.f / (1.f + __expf(-acc));
}

extern "C" void kernel_launch(void* const* d_in, const int* in_sizes, int n_in,
                              void* d_out, int out_size, void* d_ws, size_t ws_size,
                              hipStream_t stream) {
    const float* nf    = (const float*)d_in[0];
    const int*   src   = (const int*)d_in[1];
    const int*   dst   = (const int*)d_in[2];
    const int*   et    = (const int*)d_in[3];
    const int*   gid   = (const int*)d_in[4];
    const float* Ws    = (const float*)d_in[5];
    const float* bs    = (const float*)d_in[6];
    const float* W_ih  = (const float*)d_in[7];
    const float* W_hh  = (const float*)d_in[8];
    const float* b_ih  = (const float*)d_in[9];
    const float* b_hh  = (const float*)d_in[10];
    const float* W_cls = (const float*)d_in[11];
    const float* b_cls = (const float*)d_in[12];
    float* out = (float*)d_out;

    char* ws = (char*)d_ws;
    size_t off = 0;
    auto alloc = [&](size_t bytes) -> void* {
        off = (off + 255) & ~(size_t)255;
        void* p = ws + off;
        off += bytes;
        return p;
    };
    float*          h    = (float*)alloc((size_t)NN * OD * 4);          // 25.6 MB
    float*          O    = (float*)alloc((size_t)NN * LDO * 4);         // 179.2 MB
    unsigned short* hb   = (unsigned short*)alloc((size_t)NN * OD * 2); // 12.8 MB
    unsigned short* ab   = (unsigned short*)alloc((size_t)NN * OD * 2); // 12.8 MB
    int*   deg    = (int*)alloc((size_t)NN * 4);
    int*   rowp   = (int*)alloc((size_t)(NN + 1) * 4);
    int*   cursor = (int*)alloc((size_t)NN * 4);
    int*   ebase  = (int*)alloc((size_t)NE * 4);
    int*   bsum   = (int*)alloc(64 * 4);
    float* feats  = (float*)alloc((size_t)NG * 192 * 4);
    unsigned short* wsb  = (unsigned short*)alloc((size_t)4 * 16384 * 2);
    unsigned short* wihb = (unsigned short*)alloc((size_t)3 * 16384 * 2);
    unsigned short* whhb = (unsigned short*)alloc((size_t)3 * 16384 * 2);
    (void)ws_size; (void)in_sizes; (void)n_in; (void)out_size;

    // readout partials alias the (dead-by-then) O buffer: RB*12288*4 = 12.6 MB << 179 MB
    float* partial = O;

    hipMemsetAsync(deg, 0, (size_t)NN * 4, stream);

    k_cvt<<<(4 * 16384 + 255) / 256, 256, 0, stream>>>(Ws, wsb, 4 * 16384);
    k_cvt<<<(3 * 16384 + 255) / 256, 256, 0, stream>>>(W_ih, wihb, 3 * 16384);
    k_cvt<<<(3 * 16384 + 255) / 256, 256, 0, stream>>>(W_hh, whhb, 3 * 16384);

    k_init_h<<<(NN * OD + 255) / 256, 256, 0, stream>>>(nf, h, hb);
    k_count<<<(NE + 255) / 256, 256, 0, stream>>>(dst, deg);
    const int nb = (NN + 1023) / 1024;   // 49
    k_scan1<<<nb, 1024, 0, stream>>>(deg, rowp, bsum);
    k_scan2<<<1, 64, 0, stream>>>(bsum, nb);
    k_scan3<<<(NN + 255) / 256, 256, 0, stream>>>(deg, bsum, rowp, cursor);
    k_fill<<<(NE + 255) / 256, 256, 0, stream>>>(src, dst, et, cursor, ebase);

    const int mt = (NN + 127) / 128;   // 391 node tiles
    for (int s = 0; s < 8; ++s) {
        // O[:, 0..511] = Wh per etype; O[:, 512..895] = gh
        k_gemm_mfma<<<dim3(mt, 7), 256, 0, stream>>>(hb, NN, wsb, bs, 4, whhb, b_hh, O);
        k_aggregate<<<(NN + 1) / 2, 256, 0, stream>>>(O, rowp, ebase, ab);
        // gi over dead Wh region: O[:, 0..383]
        k_gemm_mfma<<<dim3(mt, 3), 256, 0, stream>>>(ab, NN, wihb, b_ih, 3, wihb, b_ih, O);
        k_gru<<<(NN * OD + 255) / 256, 256, 0, stream>>>(O, h, hb);
    }

    k_readout<<<RB, 192, 0, stream>>>(h, nf, gid, partial);
    k_reduce<<<(NG * 192 + 255) / 256, 256, 0, stream>>>(partial, feats);
    k_final<<<1, 64, 0, stream>>>(feats, W_cls, b_cls, out);
}

// Round 5
// 1101.573 us; speedup vs baseline: 2.9557x; 1.4821x over previous
//
#include <hip/hip_runtime.h>
#include <hip/hip_bf16.h>
#include <math.h>

// GGNN: N=50000 nodes, E=400000 edges, G=64 graphs, IN=64, OUT=128, 4 etypes, 8 steps.
// R5: fp16 O table (Wh/gh/gi all fp16, fp32 math), vectorized aggregate (fp16x4/lane),
//     graph-CSR register-accumulating readout.
//   - master h stays fp32 (GRU recurrence); fp16 shadows hb/ab feed the GEMMs
//   - per step: GEMM_A (hb -> [Wh x4 | gh] fp16), aggregate (fp16 gather -> ab fp16),
//     GEMM_B (ab -> gi fp16 over dead Wh region), fused GRU pointwise (2 dims/thread)
//   - readout: graph-CSR (count/scan/fill) -> 64x8 chunk blocks, register acc -> reduce

#define NN 50000
#define NE 400000
#define NG 64
#define IND 64
#define OD 128
#define LDO 896   // O row (halfs): cols 0..511 = Wh[t] (later gi in 0..383), 512..895 = gh
#define RC 8      // readout chunks per graph

typedef _Float16 f16x8 __attribute__((ext_vector_type(8)));
typedef _Float16 f16x4 __attribute__((ext_vector_type(4)));
typedef _Float16 f16x2 __attribute__((ext_vector_type(2)));
typedef float f32x4 __attribute__((ext_vector_type(4)));

__device__ inline unsigned short f2h(float x) {
    _Float16 hv = (_Float16)x;
    unsigned short u;
    __builtin_memcpy(&u, &hv, 2);
    return u;
}

// ---------------- fp32 -> fp16 weight conversion ----------------
__global__ void k_cvt(const float* __restrict__ s, unsigned short* __restrict__ d, int n) {
    int i = blockIdx.x * 256 + threadIdx.x;
    if (i < n) d[i] = f2h(s[i]);
}

// ---------------- init h = [node_features | 0] (fp32 + fp16 shadow) ----------------
__global__ void k_init_h(const float* __restrict__ nf, float* __restrict__ h,
                         unsigned short* __restrict__ hb) {
    int i = blockIdx.x * 256 + threadIdx.x;
    if (i >= NN * OD) return;
    int n = i >> 7, d = i & 127;
    float v = (d < IND) ? nf[n * IND + d] : 0.f;
    h[i] = v;
    hb[i] = f2h(v);
}

// ---------------- edge CSR build (by dst) ----------------
__global__ void k_count(const int* __restrict__ dst, int* __restrict__ deg) {
    int e = blockIdx.x * 256 + threadIdx.x;
    if (e < NE) atomicAdd(&deg[dst[e]], 1);
}

__global__ void k_scan1(const int* __restrict__ deg, int* __restrict__ rowp,
                        int* __restrict__ bsum) {
    __shared__ int buf[1024];
    int tid = threadIdx.x;
    int i = blockIdx.x * 1024 + tid;
    int v = (i < NN) ? deg[i] : 0;
    buf[tid] = v;
    __syncthreads();
    for (int off = 1; off < 1024; off <<= 1) {
        int t = (tid >= off) ? buf[tid - off] : 0;
        __syncthreads();
        buf[tid] += t;
        __syncthreads();
    }
    if (i < NN) rowp[i + 1] = buf[tid];
    if (tid == 1023) bsum[blockIdx.x] = buf[tid];
}

__global__ void k_scan2(int* __restrict__ bsum, int nb) {
    __shared__ int buf[64];
    int tid = threadIdx.x;
    int v = (tid < nb) ? bsum[tid] : 0;
    buf[tid] = v;
    __syncthreads();
    for (int off = 1; off < 64; off <<= 1) {
        int t = (tid >= off) ? buf[tid - off] : 0;
        __syncthreads();
        buf[tid] += t;
        __syncthreads();
    }
    if (tid < nb) bsum[tid] = buf[tid] - v;   // exclusive
}

__global__ void k_scan3(const int* __restrict__ deg, const int* __restrict__ bsum,
                        int* __restrict__ rowp, int* __restrict__ cursor) {
    int i = blockIdx.x * 256 + threadIdx.x;
    if (i >= NN) return;
    int incl = rowp[i + 1] + bsum[i >> 10];
    rowp[i + 1] = incl;
    cursor[i] = incl - deg[i];
    if (i == 0) rowp[0] = 0;
}

__global__ void k_fill(const int* __restrict__ src, const int* __restrict__ dst,
                       const int* __restrict__ et, int* __restrict__ cursor,
                       int* __restrict__ ebase) {
    int e = blockIdx.x * 256 + threadIdx.x;
    if (e < NE) {
        int pos = atomicAdd(&cursor[dst[e]], 1);
        ebase[pos] = src[e] * LDO + et[e] * 128;   // half-index of this edge's message row
    }
}

// ---------------- graph CSR build (by graph id), for readout ----------------
__global__ void k_gcount(const int* __restrict__ gid, int* __restrict__ gdeg) {
    __shared__ int c[NG];
    int tid = threadIdx.x;
    if (tid < NG) c[tid] = 0;
    __syncthreads();
    int n = blockIdx.x * 1024 + tid;
    if (n < NN) atomicAdd(&c[gid[n]], 1);
    __syncthreads();
    if (tid < NG && c[tid] > 0) atomicAdd(&gdeg[tid], c[tid]);
}

__global__ void k_gscan(const int* __restrict__ gdeg, int* __restrict__ growp,
                        int* __restrict__ gcur) {
    __shared__ int buf[NG];
    int tid = threadIdx.x;
    int v = gdeg[tid];
    buf[tid] = v;
    __syncthreads();
    for (int off = 1; off < NG; off <<= 1) {
        int t = (tid >= off) ? buf[tid - off] : 0;
        __syncthreads();
        buf[tid] += t;
        __syncthreads();
    }
    growp[tid + 1] = buf[tid];
    gcur[tid] = buf[tid] - v;
    if (tid == 0) growp[0] = 0;
}

__global__ void k_gfill(const int* __restrict__ gid, int* __restrict__ gcur,
                        int* __restrict__ nlist) {
    __shared__ int lcnt[NG];
    __shared__ int lbase[NG];
    int tid = threadIdx.x;
    if (tid < NG) lcnt[tid] = 0;
    __syncthreads();
    int n = blockIdx.x * 1024 + tid;
    int g = -1, rank = 0;
    if (n < NN) { g = gid[n]; rank = atomicAdd(&lcnt[g], 1); }
    __syncthreads();
    if (tid < NG && lcnt[tid] > 0) lbase[tid] = atomicAdd(&gcur[tid], lcnt[tid]);
    __syncthreads();
    if (n < NN) nlist[lbase[g] + rank] = n;
}

// ---------------- fp16 MFMA GEMM: C[m, g*128+o] = A[m,:] . W_g[o,:] + bias_g[o] -------
// A: M x 128 fp16 row-major. W group g: 128(out) x 128(in) fp16 row-major. C: fp16, ld LDO.
// Block: 256 thr (4 waves), tile 128 nodes x 128 outs, K=128 in one LDS tile.
// Verified layouts (guide §3, dtype-independent): A[m=lane&15][k=quad*8+j],
// B[k=quad*8+j][n=lane&15], C/D[row=quad*4+reg][col=lane&15].
__global__ __launch_bounds__(256) void k_gemm_mfma(
    const unsigned short* __restrict__ Ab, int M,
    const unsigned short* __restrict__ W0, const float* __restrict__ b0, int ngrp0,
    const unsigned short* __restrict__ W1, const float* __restrict__ b1,
    unsigned short* __restrict__ C) {
    __shared__ unsigned short As[128 * 136];   // stride 136 halfs = 272 B (bank-balanced)
    __shared__ unsigned short Bs[128 * 136];

    const int g = blockIdx.y;
    const unsigned short* W;
    const float* bias;
    if (g < ngrp0) { W = W0 + (size_t)g * 16384; bias = b0 + g * 128; }
    else           { W = W1 + (size_t)(g - ngrp0) * 16384; bias = b1 + (g - ngrp0) * 128; }
    const int colbase = g * 128;
    const int m0 = blockIdx.x * 128;
    const int tid = threadIdx.x;

    const uint4* A4 = (const uint4*)Ab;   // 16 uint4 per 128-col fp16 row
    const uint4* W4 = (const uint4*)W;

#pragma unroll
    for (int i = tid; i < 2048; i += 256) {
        int row = i >> 4, qq = i & 15;
        int n = m0 + row;
        uint4 va = (n < M) ? A4[(size_t)n * 16 + qq] : make_uint4(0u, 0u, 0u, 0u);
        *(uint4*)&As[row * 136 + qq * 8] = va;
        *(uint4*)&Bs[row * 136 + qq * 8] = W4[(size_t)row * 16 + qq];
    }
    __syncthreads();

    const int lane = tid & 63;
    const int w = tid >> 6;
    const int lr = lane & 15;     // row/col within 16-tile
    const int q = lane >> 4;      // quad

    float bv[8];
#pragma unroll
    for (int nt = 0; nt < 8; ++nt) bv[nt] = bias[nt * 16 + lr];

    f32x4 acc[2][8];
#pragma unroll
    for (int mt = 0; mt < 2; ++mt)
#pragma unroll
        for (int nt = 0; nt < 8; ++nt) acc[mt][nt] = (f32x4){0.f, 0.f, 0.f, 0.f};

#pragma unroll
    for (int ks = 0; ks < 4; ++ks) {
        f16x8 af[2];
#pragma unroll
        for (int mt = 0; mt < 2; ++mt)
            af[mt] = *(const f16x8*)&As[(w * 32 + mt * 16 + lr) * 136 + ks * 32 + q * 8];
        f16x8 bfr[8];
#pragma unroll
        for (int nt = 0; nt < 8; ++nt)
            bfr[nt] = *(const f16x8*)&Bs[(nt * 16 + lr) * 136 + ks * 32 + q * 8];
#pragma unroll
        for (int mt = 0; mt < 2; ++mt)
#pragma unroll
            for (int nt = 0; nt < 8; ++nt)
                acc[mt][nt] = __builtin_amdgcn_mfma_f32_16x16x32_f16(
                    af[mt], bfr[nt], acc[mt][nt], 0, 0, 0);
    }

#pragma unroll
    for (int mt = 0; mt < 2; ++mt) {
        int rowbase = m0 + w * 32 + mt * 16 + q * 4;
#pragma unroll
        for (int r = 0; r < 4; ++r) {
            int n = rowbase + r;
            if (n < M) {
                unsigned short* crow = C + (size_t)n * LDO + colbase;
#pragma unroll
                for (int nt = 0; nt < 8; ++nt)
                    crow[nt * 16 + lr] = f2h(acc[mt][nt][r] + bv[nt]);
            }
        }
    }
}

// ---------------- CSR aggregate: ab[n][d] = fp16( sum in-edge O[ebase+d] ) -------------
// 1 wave = 2 nodes; lane covers 4 dims via 8B fp16x4 loads (512 B per wave per edge).
__global__ void k_aggregate(const unsigned short* __restrict__ O,
                            const int* __restrict__ rowp, const int* __restrict__ ebase,
                            unsigned short* __restrict__ ab) {
    int wv = (blockIdx.x * 256 + threadIdx.x) >> 6;
    int lane = threadIdx.x & 63;
    int n = wv * 2 + (lane >> 5);
    if (n >= NN) return;
    int d4 = (lane & 31) * 4;
    int beg = rowp[n], end = rowp[n + 1];
    float a0 = 0.f, a1 = 0.f, a2 = 0.f, a3 = 0.f;
    for (int i = beg; i < end; ++i) {
        int b = ebase[i];
        f16x4 v = *(const f16x4*)&O[b + d4];
        a0 += (float)v[0]; a1 += (float)v[1]; a2 += (float)v[2]; a3 += (float)v[3];
    }
    f16x4 r;
    r[0] = (_Float16)a0; r[1] = (_Float16)a1; r[2] = (_Float16)a2; r[3] = (_Float16)a3;
    *(f16x4*)&ab[n * OD + d4] = r;
}

// ---------------- fused GRU pointwise (2 dims/thread) ----------------
__global__ void k_gru(const unsigned short* __restrict__ O, float* __restrict__ h,
                      unsigned short* __restrict__ hb) {
    int i = blockIdx.x * 256 + threadIdx.x;
    if (i >= NN * 64) return;
    int n = i >> 6, p = (i & 63) * 2;
    const unsigned short* r = O + (size_t)n * LDO;
    f16x2 ir = *(const f16x2*)&r[p];
    f16x2 iz = *(const f16x2*)&r[128 + p];
    f16x2 in_ = *(const f16x2*)&r[256 + p];
    f16x2 hr = *(const f16x2*)&r[512 + p];
    f16x2 hz = *(const f16x2*)&r[640 + p];
    f16x2 hn = *(const f16x2*)&r[768 + p];
    float2 hv = *(const float2*)&h[(size_t)n * OD + p];
    float2 nh;
    {
        float rg = 1.f / (1.f + __expf(-((float)ir[0] + (float)hr[0])));
        float zg = 1.f / (1.f + __expf(-((float)iz[0] + (float)hz[0])));
        float ng = tanhf((float)in_[0] + rg * (float)hn[0]);
        nh.x = (1.f - zg) * ng + zg * hv.x;
        rg = 1.f / (1.f + __expf(-((float)ir[1] + (float)hr[1])));
        zg = 1.f / (1.f + __expf(-((float)iz[1] + (float)hz[1])));
        ng = tanhf((float)in_[1] + rg * (float)hn[1]);
        nh.y = (1.f - zg) * ng + zg * hv.y;
    }
    *(float2*)&h[(size_t)n * OD + p] = nh;
    f16x2 hb2; hb2[0] = (_Float16)nh.x; hb2[1] = (_Float16)nh.y;
    *(f16x2*)&hb[(size_t)n * OD + p] = hb2;
}

// ---------------- graph readout: register acc over graph-sorted node list --------------
// grid = NG*RC blocks, 192 threads; block (g,c) sums chunk c of graph g's nodes.
__global__ void k_readout(const float* __restrict__ h, const float* __restrict__ nf,
                          const int* __restrict__ nlist, const int* __restrict__ growp,
                          float* __restrict__ partial) {
    int g = blockIdx.x >> 3, c = blockIdx.x & (RC - 1);
    int d = threadIdx.x;
    int s = growp[g], e = growp[g + 1], len = e - s;
    int i0 = s + (int)((long long)len * c / RC);
    int i1 = s + (int)((long long)len * (c + 1) / RC);
    float acc = 0.f;
    for (int i = i0; i < i1; ++i) {
        int n = nlist[i];
        acc += (d < OD) ? h[(size_t)n * OD + d] : nf[(size_t)n * IND + (d - OD)];
    }
    partial[(size_t)blockIdx.x * 192 + d] = acc;
}

__global__ void k_reduce(const float* __restrict__ partial, float* __restrict__ feats) {
    int i = blockIdx.x * 256 + threadIdx.x;
    if (i >= NG * 192) return;
    int g = i / 192, d = i % 192;
    float s = 0.f;
    for (int c = 0; c < RC; ++c) s += partial[(size_t)(g * RC + c) * 192 + d];
    feats[i] = s;
}

__global__ void k_final(const float* __restrict__ feats, const float* __restrict__ W_cls,
                        const float* __restrict__ b_cls, float* __restrict__ out) {
    int g = threadIdx.x;
    if (g >= NG) return;
    float acc = b_cls[0];
    for (int d = 0; d < 192; ++d) acc += feats[g * 192 + d] * W_cls[d];
    out[g] = 1.f / (1.f + __expf(-acc));
}

extern "C" void kernel_launch(void* const* d_in, const int* in_sizes, int n_in,
                              void* d_out, int out_size, void* d_ws, size_t ws_size,
                              hipStream_t stream) {
    const float* nf    = (const float*)d_in[0];
    const int*   src   = (const int*)d_in[1];
    const int*   dst   = (const int*)d_in[2];
    const int*   et    = (const int*)d_in[3];
    const int*   gid   = (const int*)d_in[4];
    const float* Ws    = (const float*)d_in[5];
    const float* bs    = (const float*)d_in[6];
    const float* W_ih  = (const float*)d_in[7];
    const float* W_hh  = (const float*)d_in[8];
    const float* b_ih  = (const float*)d_in[9];
    const float* b_hh  = (const float*)d_in[10];
    const float* W_cls = (const float*)d_in[11];
    const float* b_cls = (const float*)d_in[12];
    float* out = (float*)d_out;

    char* ws = (char*)d_ws;
    size_t off = 0;
    auto alloc = [&](size_t bytes) -> void* {
        off = (off + 255) & ~(size_t)255;
        void* p = ws + off;
        off += bytes;
        return p;
    };
    float*          h    = (float*)alloc((size_t)NN * OD * 4);              // 25.6 MB
    unsigned short* O    = (unsigned short*)alloc((size_t)NN * LDO * 2);    // 89.6 MB
    unsigned short* hb   = (unsigned short*)alloc((size_t)NN * OD * 2);     // 12.8 MB
    unsigned short* ab   = (unsigned short*)alloc((size_t)NN * OD * 2);     // 12.8 MB
    int*   deg    = (int*)alloc((size_t)NN * 4);
    int*   rowp   = (int*)alloc((size_t)(NN + 1) * 4);
    int*   cursor = (int*)alloc((size_t)NN * 4);
    int*   ebase  = (int*)alloc((size_t)NE * 4);
    int*   bsum   = (int*)alloc(64 * 4);
    int*   gdeg   = (int*)alloc(NG * 4);
    int*   growp  = (int*)alloc((NG + 1) * 4);
    int*   gcur   = (int*)alloc(NG * 4);
    int*   nlist  = (int*)alloc((size_t)NN * 4);
    float* feats  = (float*)alloc((size_t)NG * 192 * 4);
    unsigned short* wsb  = (unsigned short*)alloc((size_t)4 * 16384 * 2);
    unsigned short* wihb = (unsigned short*)alloc((size_t)3 * 16384 * 2);
    unsigned short* whhb = (unsigned short*)alloc((size_t)3 * 16384 * 2);
    (void)ws_size; (void)in_sizes; (void)n_in; (void)out_size;

    // readout partials alias the (dead-by-then) O buffer: 512*192*4 = 393 KB << 89.6 MB
    float* partial = (float*)O;

    hipMemsetAsync(deg, 0, (size_t)NN * 4, stream);
    hipMemsetAsync(gdeg, 0, NG * 4, stream);

    k_cvt<<<(4 * 16384 + 255) / 256, 256, 0, stream>>>(Ws, wsb, 4 * 16384);
    k_cvt<<<(3 * 16384 + 255) / 256, 256, 0, stream>>>(W_ih, wihb, 3 * 16384);
    k_cvt<<<(3 * 16384 + 255) / 256, 256, 0, stream>>>(W_hh, whhb, 3 * 16384);

    k_init_h<<<(NN * OD + 255) / 256, 256, 0, stream>>>(nf, h, hb);
    k_count<<<(NE + 255) / 256, 256, 0, stream>>>(dst, deg);
    const int nb = (NN + 1023) / 1024;   // 49
    k_scan1<<<nb, 1024, 0, stream>>>(deg, rowp, bsum);
    k_scan2<<<1, 64, 0, stream>>>(bsum, nb);
    k_scan3<<<(NN + 255) / 256, 256, 0, stream>>>(deg, bsum, rowp, cursor);
    k_fill<<<(NE + 255) / 256, 256, 0, stream>>>(src, dst, et, cursor, ebase);

    k_gcount<<<nb, 1024, 0, stream>>>(gid, gdeg);
    k_gscan<<<1, NG, 0, stream>>>(gdeg, growp, gcur);
    k_gfill<<<nb, 1024, 0, stream>>>(gid, gcur, nlist);

    const int mt = (NN + 127) / 128;   // 391 node tiles
    const int aggblk = (NN * 32 + 255) / 256;   // 2 nodes per wave
    for (int s = 0; s < 8; ++s) {
        // O[:, 0..511] = Wh per etype; O[:, 512..895] = gh
        k_gemm_mfma<<<dim3(mt, 7), 256, 0, stream>>>(hb, NN, wsb, bs, 4, whhb, b_hh, O);
        k_aggregate<<<aggblk, 256, 0, stream>>>(O, rowp, ebase, ab);
        // gi over dead Wh region: O[:, 0..383]
        k_gemm_mfma<<<dim3(mt, 3), 256, 0, stream>>>(ab, NN, wihb, b_ih, 3, wihb, b_ih, O);
        k_gru<<<(NN * 64 + 255) / 256, 256, 0, stream>>>(O, h, hb);
    }

    k_readout<<<NG * RC, 192, 0, stream>>>(h, nf, nlist, growp, partial);
    k_reduce<<<(NG * 192 + 255) / 256, 256, 0, stream>>>(partial, feats);
    k_final<<<1, 64, 0, stream>>>(feats, W_cls, b_cls, out);
}